// Round 1
// baseline (383.200 us; speedup 1.0000x reference)
//
#include <hip/hip_runtime.h>
#include <hip/hip_bf16.h>
#include <math.h>

#define N_SKILLS 16
#define RLORA 16
#define IN_F 1024
#define OUT_F 1024
#define KD 1024
#define ND 1024
#define BM 128
#define BN 128
#define BK 32

typedef __attribute__((ext_vector_type(8))) short s16x8;
typedef __attribute__((ext_vector_type(4))) float f32x4;

__device__ __forceinline__ unsigned short f2bf(float f) {
  unsigned int u = __float_as_uint(f);
  u += 0x7fffu + ((u >> 16) & 1u);
  return (unsigned short)(u >> 16);
}

// ---------------------------------------------------------------------------
// Kernel 1: routing logits -> per-sample LoRA weights wA (B,IN_F,R), wB (B,R,OUT_F)
// grid 32 blocks x 256 thr: blocks 0..15 -> wA[b], 16..31 -> wB[b]
// ---------------------------------------------------------------------------
__global__ void route_wab_kernel(const float* __restrict__ skill_logits,
                                 const int* __restrict__ task_ids,
                                 const float* __restrict__ Askills,
                                 const float* __restrict__ Bskills,
                                 float* __restrict__ wA, float* __restrict__ wB) {
  __shared__ float l[N_SKILLS];
  const int bx = blockIdx.x;
  const int b = bx & 15;
  const int doB = bx >> 4;
  const int tid = threadIdx.x;
  if (tid == 0) {
    int t = task_ids[b];
    float tmp[N_SKILLS];
    float s = 0.f;
    for (int k = 0; k < N_SKILLS; ++k) {
      float v = 1.f / (1.f + expf(-skill_logits[t * N_SKILLS + k]));
      tmp[k] = v;
      s += v;
    }
    float inv = 1.f / (s + 1e-12f);
    for (int k = 0; k < N_SKILLS; ++k) l[k] = tmp[k] * inv;
  }
  __syncthreads();
  const float* src = doB ? Bskills : Askills;
  float* dst = (doB ? wB : wA) + b * 16384;
  for (int j = tid; j < 16384; j += 256) {
    float acc = 0.f;
#pragma unroll
    for (int k = 0; k < N_SKILLS; ++k) acc += l[k] * src[k * 16384 + j];
    dst[j] = acc;
  }
}

// ---------------------------------------------------------------------------
// Kernel 2: W_eff_bt[b][o][i] = weight[o][i] + (1/R) * sum_r wA[b][i][r]*wB[b][r][o]
// stored bf16, [b][o][i] row-major (B^T layout for the GEMM).
// grid (256, 16): blockIdx.x = ob*4+ib (64 o-blocks of 16 rows, 4 i-blocks of 256)
// ---------------------------------------------------------------------------
__global__ void weff_kernel(const float* __restrict__ weight,
                            const float* __restrict__ wA,
                            const float* __restrict__ wB,
                            unsigned short* __restrict__ Weff) {
  __shared__ float wBs[RLORA][16];
  const int b = blockIdx.y;
  const int ob = blockIdx.x >> 2;
  const int ib = blockIdx.x & 3;
  const int tid = threadIdx.x;
  const int o0 = ob * 16;
  const int i = ib * 256 + tid;
  {
    int r = tid >> 4, oo = tid & 15;
    wBs[r][oo] = wB[b * 16384 + r * OUT_F + o0 + oo];
  }
  __syncthreads();
  float wAi[RLORA];
#pragma unroll
  for (int r = 0; r < RLORA; ++r) wAi[r] = wA[b * 16384 + i * RLORA + r];
  const float scaling = 1.0f / RLORA;
#pragma unroll
  for (int oo = 0; oo < 16; ++oo) {
    float acc = 0.f;
#pragma unroll
    for (int r = 0; r < RLORA; ++r) acc += wAi[r] * wBs[r][oo];
    float v = weight[(size_t)(o0 + oo) * IN_F + i] + scaling * acc;
    Weff[(size_t)b * (ND * KD) + (size_t)(o0 + oo) * KD + i] = f2bf(v);
  }
}

// ---------------------------------------------------------------------------
// Kernel 3: main GEMM  C[m][n] = sum_k A[m][k]*Weff[b][n][k] + bias[n]
// A fp32 (65536 x 1024) converted inline to bf16; Weff bf16 per-batch.
// 128x128 tile, BK=32, 4 waves (2x2), 4x4 16x16x32 MFMA frags per wave.
// B via global_load_lds(16B); A reg-staged (load early, cvt+ds_write late).
// ---------------------------------------------------------------------------
#define GLD(gsrc, ldst)                                                        \
  __builtin_amdgcn_global_load_lds(                                            \
      (const __attribute__((address_space(1))) unsigned int*)(gsrc),           \
      (__attribute__((address_space(3))) unsigned int*)(ldst), 16, 0, 0)

__global__ __launch_bounds__(256) void gemm_kernel(
    const float* __restrict__ A, const unsigned short* __restrict__ Weff,
    const float* __restrict__ bias, float* __restrict__ C) {
  __shared__ __align__(16) unsigned short As[2][BM][BK];
  __shared__ __align__(16) unsigned short Bs[2][BN][BK];

  // XCD-aware swizzle (4096 blocks, 4096%8==0 -> bijective)
  const int orig = blockIdx.x;
  const int bid = (orig & 7) * 512 + (orig >> 3);
  const int mt = bid >> 3;
  const int nt = bid & 7;
  const int m0 = mt * BM;
  const int n0 = nt * BN;
  const int batch = m0 >> 12;  // 4096 rows per batch
  const unsigned short* Bw = Weff + (size_t)batch * (ND * KD);

  const int tid = threadIdx.x;
  const int lane = tid & 63;
  const int wid = tid >> 6;
  const int wr = wid >> 1;
  const int wc = wid & 1;
  const int l15 = lane & 15;
  const int kseg = (lane >> 4) * 8;

  // A staging: thread -> (row, 16-float half-row)
  const int arow = tid >> 1;
  const int acol = (tid & 1) * 16;
  const float* aptr = A + (size_t)(m0 + arow) * KD + acol;

  // B staging via global_load_lds: wave wid fills 2 chunks of 1KB (16 rows x 64B)
  // lane l -> row (l>>2), k-seg (l&3)*8 within chunk
  const unsigned short* bptr1 =
      Bw + (size_t)(n0 + wid * 32 + (lane >> 2)) * KD + (lane & 3) * 8;

  f32x4 acc[4][4] = {};

  // prologue: stage tile 0 into buffer 0
  {
    f32x4 av0 = *(const f32x4*)(aptr);
    f32x4 av1 = *(const f32x4*)(aptr + 4);
    f32x4 av2 = *(const f32x4*)(aptr + 8);
    f32x4 av3 = *(const f32x4*)(aptr + 12);
    GLD(bptr1, &Bs[0][wid * 32][0]);
    GLD(bptr1 + (size_t)16 * KD, &Bs[0][wid * 32 + 16][0]);
    s16x8 lo, hi;
#pragma unroll
    for (int j = 0; j < 4; ++j) {
      lo[j] = (short)f2bf(av0[j]);
      lo[j + 4] = (short)f2bf(av1[j]);
      hi[j] = (short)f2bf(av2[j]);
      hi[j + 4] = (short)f2bf(av3[j]);
    }
    *(s16x8*)&As[0][arow][acol] = lo;
    *(s16x8*)&As[0][arow][acol + 8] = hi;
  }
  __syncthreads();

  for (int kt = 0; kt < KD / BK; ++kt) {
    const int buf = kt & 1;
    f32x4 av0, av1, av2, av3;
    const bool pre = (kt + 1 < KD / BK);
    if (pre) {
      const float* ap = aptr + (kt + 1) * BK;
      av0 = *(const f32x4*)(ap);
      av1 = *(const f32x4*)(ap + 4);
      av2 = *(const f32x4*)(ap + 8);
      av3 = *(const f32x4*)(ap + 12);
      const unsigned short* bp = bptr1 + (size_t)(kt + 1) * BK;
      GLD(bp, &Bs[buf ^ 1][wid * 32][0]);
      GLD(bp + (size_t)16 * KD, &Bs[buf ^ 1][wid * 32 + 16][0]);
    }
    s16x8 af[4], bfr[4];
#pragma unroll
    for (int m = 0; m < 4; ++m)
      af[m] = *(const s16x8*)&As[buf][wr * 64 + m * 16 + l15][kseg];
#pragma unroll
    for (int n = 0; n < 4; ++n)
      bfr[n] = *(const s16x8*)&Bs[buf][wc * 64 + n * 16 + l15][kseg];
#pragma unroll
    for (int m = 0; m < 4; ++m)
#pragma unroll
      for (int n = 0; n < 4; ++n)
        acc[m][n] = __builtin_amdgcn_mfma_f32_16x16x32_bf16(af[m], bfr[n],
                                                            acc[m][n], 0, 0, 0);
    if (pre) {
      s16x8 lo, hi;
#pragma unroll
      for (int j = 0; j < 4; ++j) {
        lo[j] = (short)f2bf(av0[j]);
        lo[j + 4] = (short)f2bf(av1[j]);
        hi[j] = (short)f2bf(av2[j]);
        hi[j + 4] = (short)f2bf(av3[j]);
      }
      *(s16x8*)&As[buf ^ 1][arow][acol] = lo;
      *(s16x8*)&As[buf ^ 1][arow][acol + 8] = hi;
    }
    __syncthreads();
  }

  // epilogue: bias add + store fp32
#pragma unroll
  for (int n = 0; n < 4; ++n) {
    const int col = n0 + wc * 64 + n * 16 + l15;
    const float bv = bias[col];
#pragma unroll
    for (int m = 0; m < 4; ++m) {
      const int row = m0 + wr * 64 + m * 16 + (lane >> 4) * 4;
#pragma unroll
      for (int j = 0; j < 4; ++j)
        C[(size_t)(row + j) * ND + col] = acc[m][n][j] + bv;
    }
  }
}

// ---------------------------------------------------------------------------
extern "C" void kernel_launch(void* const* d_in, const int* in_sizes, int n_in,
                              void* d_out, int out_size, void* d_ws,
                              size_t ws_size, hipStream_t stream) {
  const float* input = (const float*)d_in[0];
  const float* skill_logits = (const float*)d_in[1];
  const float* weight = (const float*)d_in[2];
  const float* bias = (const float*)d_in[3];
  const float* Askills = (const float*)d_in[4];
  const float* Bskills = (const float*)d_in[5];
  const int* task_ids = (const int*)d_in[6];

  float* wA = (float*)d_ws;                       // 16*16384 f32 = 1 MB
  float* wB = wA + 16 * 16384;                    // 1 MB
  unsigned short* Weff = (unsigned short*)(wB + 16 * 16384);  // 16M bf16 = 32 MB

  route_wab_kernel<<<32, 256, 0, stream>>>(skill_logits, task_ids, Askills,
                                           Bskills, wA, wB);
  weff_kernel<<<dim3(256, 16), 256, 0, stream>>>(weight, wA, wB, Weff);
  gemm_kernel<<<4096, 256, 0, stream>>>(input, Weff, bias, (float*)d_out);
}

// Round 2
// 363.775 us; speedup vs baseline: 1.0534x; 1.0534x over previous
//
#include <hip/hip_runtime.h>
#include <hip/hip_bf16.h>
#include <math.h>

#define N_SKILLS 16
#define RLORA 16
#define IN_F 1024
#define OUT_F 1024
#define KD 1024
#define ND 1024

typedef __attribute__((ext_vector_type(8))) short s16x8;
typedef __attribute__((ext_vector_type(4))) float f32x4;

__device__ __forceinline__ unsigned short f2bf(float f) {
  unsigned int u = __float_as_uint(f);
  u += 0x7fffu + ((u >> 16) & 1u);
  return (unsigned short)(u >> 16);
}

#define GLD(gsrc, ldst)                                                        \
  __builtin_amdgcn_global_load_lds(                                            \
      (const __attribute__((address_space(1))) unsigned int*)(gsrc),           \
      (__attribute__((address_space(3))) unsigned int*)(ldst), 16, 0, 0)

// ---------------------------------------------------------------------------
// Kernel 1: routing -> per-sample LoRA weights wA (B,IN_F,R), wB (B,R,OUT_F)
// ---------------------------------------------------------------------------
__global__ void route_wab_kernel(const float* __restrict__ skill_logits,
                                 const int* __restrict__ task_ids,
                                 const float* __restrict__ Askills,
                                 const float* __restrict__ Bskills,
                                 float* __restrict__ wA, float* __restrict__ wB) {
  __shared__ float l[N_SKILLS];
  const int bx = blockIdx.x;
  const int b = bx & 15;
  const int doB = bx >> 4;
  const int tid = threadIdx.x;
  if (tid == 0) {
    int t = task_ids[b];
    float tmp[N_SKILLS];
    float s = 0.f;
    for (int k = 0; k < N_SKILLS; ++k) {
      float v = 1.f / (1.f + expf(-skill_logits[t * N_SKILLS + k]));
      tmp[k] = v;
      s += v;
    }
    float inv = 1.f / (s + 1e-12f);
    for (int k = 0; k < N_SKILLS; ++k) l[k] = tmp[k] * inv;
  }
  __syncthreads();
  const float* src = doB ? Bskills : Askills;
  float* dst = (doB ? wB : wA) + b * 16384;
  for (int j = tid; j < 16384; j += 256) {
    float acc = 0.f;
#pragma unroll
    for (int k = 0; k < N_SKILLS; ++k) acc += l[k] * src[k * 16384 + j];
    dst[j] = acc;
  }
}

// ---------------------------------------------------------------------------
// Kernel 2a: A fp32 -> bf16, re-laid out in per-(mt,kt) tile LDS-image order.
// Tile (mt,kt) = 128 rows x 32 k, stored as 512 x 16B chunks, chunk c =
// kc*128+row (kc = k/8). Block = one tile; coalesced read, LDS transpose,
// coalesced write.
// ---------------------------------------------------------------------------
__global__ void aconv_kernel(const float* __restrict__ A,
                             unsigned short* __restrict__ At) {
  __shared__ unsigned short tile[4096];
  const int t = blockIdx.x;  // mt*32 + kt
  const int mt = t >> 5, kt = t & 31;
  const int tid = threadIdx.x;
  const int row = tid >> 1, half = tid & 1;
  const float* src = A + (size_t)(mt * 128 + row) * KD + kt * 32 + half * 16;
  f32x4 v0 = *(const f32x4*)(src);
  f32x4 v1 = *(const f32x4*)(src + 4);
  f32x4 v2 = *(const f32x4*)(src + 8);
  f32x4 v3 = *(const f32x4*)(src + 12);
  s16x8 lo, hi;
#pragma unroll
  for (int j = 0; j < 4; ++j) {
    lo[j] = (short)f2bf(v0[j]);
    lo[j + 4] = (short)f2bf(v1[j]);
    hi[j] = (short)f2bf(v2[j]);
    hi[j + 4] = (short)f2bf(v3[j]);
  }
  *(s16x8*)&tile[((half * 2) * 128 + row) * 8] = lo;
  *(s16x8*)&tile[((half * 2 + 1) * 128 + row) * 8] = hi;
  __syncthreads();
  unsigned short* dst = At + (size_t)t * 4096;
  *(s16x8*)&dst[tid * 16] = *(const s16x8*)&tile[tid * 16];
  *(s16x8*)&dst[tid * 16 + 8] = *(const s16x8*)&tile[tid * 16 + 8];
}

// ---------------------------------------------------------------------------
// Kernel 2b: W_eff = weight + (1/R)*(wA@wB)^T, bf16, tiled LDS-image layout.
// Block = (b, nt, kt): 128 o-rows x 32 i. Tile index = b*256 + nt*32 + kt.
// ---------------------------------------------------------------------------
__global__ void weff_tiled_kernel(const float* __restrict__ weight,
                                  const float* __restrict__ wA,
                                  const float* __restrict__ wB,
                                  unsigned short* __restrict__ Wt) {
  __shared__ float wBs[16][128];
  __shared__ float wAs[32][16];
  __shared__ unsigned short tile[4096];
  const int t = blockIdx.x;  // b*256 + nt*32 + kt
  const int b = t >> 8;
  const int nt = (t >> 5) & 7;
  const int kt = t & 31;
  const int tid = threadIdx.x;
  for (int j = tid; j < 2048; j += 256)
    wBs[j >> 7][j & 127] =
        wB[b * 16384 + (j >> 7) * OUT_F + nt * 128 + (j & 127)];
  for (int j = tid; j < 512; j += 256)
    wAs[j >> 4][j & 15] =
        wA[b * 16384 + (kt * 32 + (j >> 4)) * RLORA + (j & 15)];
  __syncthreads();
  const int o = tid >> 1, half = tid & 1;
  const float* wrow =
      weight + (size_t)(nt * 128 + o) * IN_F + kt * 32 + half * 16;
  f32x4 w0 = *(const f32x4*)(wrow);
  f32x4 w1 = *(const f32x4*)(wrow + 4);
  f32x4 w2 = *(const f32x4*)(wrow + 8);
  f32x4 w3 = *(const f32x4*)(wrow + 12);
  float wv[16];
#pragma unroll
  for (int j = 0; j < 4; ++j) {
    wv[j] = w0[j];
    wv[j + 4] = w1[j];
    wv[j + 8] = w2[j];
    wv[j + 12] = w3[j];
  }
  float wbo[16];
#pragma unroll
  for (int r = 0; r < 16; ++r) wbo[r] = wBs[r][o];
  unsigned short res[16];
#pragma unroll
  for (int j = 0; j < 16; ++j) {
    const int il = half * 16 + j;
    float acc = 0.f;
#pragma unroll
    for (int r = 0; r < 16; ++r) acc += wAs[il][r] * wbo[r];
    res[j] = f2bf(wv[j] + acc * 0.0625f);
  }
  s16x8 lo, hi;
#pragma unroll
  for (int j = 0; j < 8; ++j) {
    lo[j] = (short)res[j];
    hi[j] = (short)res[j + 8];
  }
  *(s16x8*)&tile[((half * 2) * 128 + o) * 8] = lo;
  *(s16x8*)&tile[((half * 2 + 1) * 128 + o) * 8] = hi;
  __syncthreads();
  unsigned short* dst = Wt + (size_t)t * 4096;
  *(s16x8*)&dst[tid * 16] = *(const s16x8*)&tile[tid * 16];
  *(s16x8*)&dst[tid * 16 + 8] = *(const s16x8*)&tile[tid * 16 + 8];
}

// ---------------------------------------------------------------------------
// Kernel 3: GEMM, both operands pre-tiled bf16. 128x128 tile, BK=32,
// 4 waves (2x2), 4x4 16x16x32 MFMA frags. All staging via global_load_lds(16B)
// from contiguous tile images; conflict-free chunk layout.
// ---------------------------------------------------------------------------
__global__ __launch_bounds__(256) void gemm2_kernel(
    const unsigned short* __restrict__ At, const unsigned short* __restrict__ Wt,
    const float* __restrict__ bias, float* __restrict__ C) {
  __shared__ __align__(16) unsigned short As[2][4096];
  __shared__ __align__(16) unsigned short Bs[2][4096];
  const int orig = blockIdx.x;
  const int bid = (orig & 7) * 512 + (orig >> 3);  // XCD swizzle (4096%8==0)
  const int mt = bid >> 3;
  const int nt = bid & 7;
  const int batch = mt >> 5;  // 32 m-tiles per batch
  const unsigned short* Abase = At + (size_t)mt * 32 * 4096;
  const unsigned short* Bbase = Wt + (size_t)(batch * 256 + nt * 32) * 4096;

  const int tid = threadIdx.x;
  const int lane = tid & 63;
  const int wid = tid >> 6;
  const int wr = wid >> 1;
  const int wc = wid & 1;
  const int l15 = lane & 15;
  const int kq = lane >> 4;
  const int soff = wid * 512 + lane * 8;  // per-lane src offset (shorts)
  const int doff = wid * 512;             // wave-uniform LDS dst (shorts)

  f32x4 acc[4][4] = {};

  GLD(Abase + soff, &As[0][doff]);
  GLD(Abase + 2048 + soff, &As[0][2048 + doff]);
  GLD(Bbase + soff, &Bs[0][doff]);
  GLD(Bbase + 2048 + soff, &Bs[0][2048 + doff]);
  __syncthreads();

  for (int kt = 0; kt < 32; ++kt) {
    const int buf = kt & 1;
    if (kt < 31) {
      const unsigned short* an = Abase + (size_t)(kt + 1) * 4096;
      const unsigned short* bn = Bbase + (size_t)(kt + 1) * 4096;
      GLD(an + soff, &As[buf ^ 1][doff]);
      GLD(an + 2048 + soff, &As[buf ^ 1][2048 + doff]);
      GLD(bn + soff, &Bs[buf ^ 1][doff]);
      GLD(bn + 2048 + soff, &Bs[buf ^ 1][2048 + doff]);
    }
    s16x8 af[4], bfrag[4];
#pragma unroll
    for (int m = 0; m < 4; ++m)
      af[m] = *(const s16x8*)&As[buf][(kq * 128 + wr * 64 + m * 16 + l15) * 8];
#pragma unroll
    for (int n = 0; n < 4; ++n)
      bfrag[n] =
          *(const s16x8*)&Bs[buf][(kq * 128 + wc * 64 + n * 16 + l15) * 8];
#pragma unroll
    for (int m = 0; m < 4; ++m)
#pragma unroll
      for (int n = 0; n < 4; ++n)
        acc[m][n] = __builtin_amdgcn_mfma_f32_16x16x32_bf16(af[m], bfrag[n],
                                                            acc[m][n], 0, 0, 0);
    __syncthreads();
  }

  const int m0 = mt * 128, n0 = nt * 128;
#pragma unroll
  for (int n = 0; n < 4; ++n) {
    const int col = n0 + wc * 64 + n * 16 + l15;
    const float bv = bias[col];
#pragma unroll
    for (int m = 0; m < 4; ++m) {
      const int row = m0 + wr * 64 + m * 16 + kq * 4;
#pragma unroll
      for (int j = 0; j < 4; ++j)
        C[(size_t)(row + j) * ND + col] = acc[m][n][j] + bv;
    }
  }
}

// ---------------------------------------------------------------------------
// Fallback path (round-1 kernels) if ws_size is too small for the tiled path.
// ---------------------------------------------------------------------------
__global__ void weff_fb_kernel(const float* __restrict__ weight,
                               const float* __restrict__ wA,
                               const float* __restrict__ wB,
                               unsigned short* __restrict__ Weff) {
  __shared__ float wBs[RLORA][16];
  const int b = blockIdx.y;
  const int ob = blockIdx.x >> 2;
  const int ib = blockIdx.x & 3;
  const int tid = threadIdx.x;
  const int o0 = ob * 16;
  const int i = ib * 256 + tid;
  {
    int r = tid >> 4, oo = tid & 15;
    wBs[r][oo] = wB[b * 16384 + r * OUT_F + o0 + oo];
  }
  __syncthreads();
  float wAi[RLORA];
#pragma unroll
  for (int r = 0; r < RLORA; ++r) wAi[r] = wA[b * 16384 + i * RLORA + r];
#pragma unroll
  for (int oo = 0; oo < 16; ++oo) {
    float acc = 0.f;
#pragma unroll
    for (int r = 0; r < RLORA; ++r) acc += wAi[r] * wBs[r][oo];
    float v = weight[(size_t)(o0 + oo) * IN_F + i] + 0.0625f * acc;
    Weff[(size_t)b * (ND * KD) + (size_t)(o0 + oo) * KD + i] = f2bf(v);
  }
}

__global__ __launch_bounds__(256) void gemm_fb_kernel(
    const float* __restrict__ A, const unsigned short* __restrict__ Weff,
    const float* __restrict__ bias, float* __restrict__ C) {
  __shared__ __align__(16) unsigned short As[2][128][32];
  __shared__ __align__(16) unsigned short Bs[2][128][32];
  const int orig = blockIdx.x;
  const int bid = (orig & 7) * 512 + (orig >> 3);
  const int mt = bid >> 3;
  const int nt = bid & 7;
  const int m0 = mt * 128;
  const int n0 = nt * 128;
  const int batch = m0 >> 12;
  const unsigned short* Bw = Weff + (size_t)batch * (ND * KD);
  const int tid = threadIdx.x;
  const int lane = tid & 63;
  const int wid = tid >> 6;
  const int wr = wid >> 1;
  const int wc = wid & 1;
  const int l15 = lane & 15;
  const int kseg = (lane >> 4) * 8;
  const int arow = tid >> 1;
  const int acol = (tid & 1) * 16;
  const float* aptr = A + (size_t)(m0 + arow) * KD + acol;
  const unsigned short* bptr1 =
      Bw + (size_t)(n0 + wid * 32 + (lane >> 2)) * KD + (lane & 3) * 8;
  f32x4 acc[4][4] = {};
  {
    f32x4 av0 = *(const f32x4*)(aptr);
    f32x4 av1 = *(const f32x4*)(aptr + 4);
    f32x4 av2 = *(const f32x4*)(aptr + 8);
    f32x4 av3 = *(const f32x4*)(aptr + 12);
    GLD(bptr1, &Bs[0][wid * 32][0]);
    GLD(bptr1 + (size_t)16 * KD, &Bs[0][wid * 32 + 16][0]);
    s16x8 lo, hi;
#pragma unroll
    for (int j = 0; j < 4; ++j) {
      lo[j] = (short)f2bf(av0[j]);
      lo[j + 4] = (short)f2bf(av1[j]);
      hi[j] = (short)f2bf(av2[j]);
      hi[j + 4] = (short)f2bf(av3[j]);
    }
    *(s16x8*)&As[0][arow][acol] = lo;
    *(s16x8*)&As[0][arow][acol + 8] = hi;
  }
  __syncthreads();
  for (int kt = 0; kt < 32; ++kt) {
    const int buf = kt & 1;
    f32x4 av0, av1, av2, av3;
    const bool pre = (kt + 1 < 32);
    if (pre) {
      const float* ap = aptr + (kt + 1) * 32;
      av0 = *(const f32x4*)(ap);
      av1 = *(const f32x4*)(ap + 4);
      av2 = *(const f32x4*)(ap + 8);
      av3 = *(const f32x4*)(ap + 12);
      const unsigned short* bp = bptr1 + (size_t)(kt + 1) * 32;
      GLD(bp, &Bs[buf ^ 1][wid * 32][0]);
      GLD(bp + (size_t)16 * KD, &Bs[buf ^ 1][wid * 32 + 16][0]);
    }
    s16x8 af[4], bfr[4];
#pragma unroll
    for (int m = 0; m < 4; ++m)
      af[m] = *(const s16x8*)&As[buf][wr * 64 + m * 16 + l15][kseg];
#pragma unroll
    for (int n = 0; n < 4; ++n)
      bfr[n] = *(const s16x8*)&Bs[buf][wc * 64 + n * 16 + l15][kseg];
#pragma unroll
    for (int m = 0; m < 4; ++m)
#pragma unroll
      for (int n = 0; n < 4; ++n)
        acc[m][n] = __builtin_amdgcn_mfma_f32_16x16x32_bf16(af[m], bfr[n],
                                                            acc[m][n], 0, 0, 0);
    if (pre) {
      s16x8 lo, hi;
#pragma unroll
      for (int j = 0; j < 4; ++j) {
        lo[j] = (short)f2bf(av0[j]);
        lo[j + 4] = (short)f2bf(av1[j]);
        hi[j] = (short)f2bf(av2[j]);
        hi[j + 4] = (short)f2bf(av3[j]);
      }
      *(s16x8*)&As[buf ^ 1][arow][acol] = lo;
      *(s16x8*)&As[buf ^ 1][arow][acol + 8] = hi;
    }
    __syncthreads();
  }
#pragma unroll
  for (int n = 0; n < 4; ++n) {
    const int col = n0 + wc * 64 + n * 16 + l15;
    const float bv = bias[col];
#pragma unroll
    for (int m = 0; m < 4; ++m) {
      const int row = m0 + wr * 64 + m * 16 + (lane >> 4) * 4;
#pragma unroll
      for (int j = 0; j < 4; ++j)
        C[(size_t)(row + j) * ND + col] = acc[m][n][j] + bv;
    }
  }
}

// ---------------------------------------------------------------------------
extern "C" void kernel_launch(void* const* d_in, const int* in_sizes, int n_in,
                              void* d_out, int out_size, void* d_ws,
                              size_t ws_size, hipStream_t stream) {
  const float* input = (const float*)d_in[0];
  const float* skill_logits = (const float*)d_in[1];
  const float* weight = (const float*)d_in[2];
  const float* bias = (const float*)d_in[3];
  const float* Askills = (const float*)d_in[4];
  const float* Bskills = (const float*)d_in[5];
  const int* task_ids = (const int*)d_in[6];

  float* wA = (float*)d_ws;                                    // 1 MB
  float* wB = wA + 16 * 16384;                                 // 1 MB
  unsigned short* Weff = (unsigned short*)(wB + 16 * 16384);   // 32 MB
  unsigned short* At = Weff + 16ull * 1024 * 1024;             // 128 MB

  const size_t NEED = 2097152ull + 33554432ull + 134217728ull;  // 162 MB

  route_wab_kernel<<<32, 256, 0, stream>>>(skill_logits, task_ids, Askills,
                                           Bskills, wA, wB);
  if (ws_size >= NEED) {
    aconv_kernel<<<16384, 256, 0, stream>>>(input, At);
    weff_tiled_kernel<<<4096, 256, 0, stream>>>(weight, wA, wB, Weff);
    gemm2_kernel<<<4096, 256, 0, stream>>>(At, Weff, bias, (float*)d_out);
  } else {
    weff_fb_kernel<<<dim3(256, 16), 256, 0, stream>>>(weight, wA, wB, Weff);
    gemm_fb_kernel<<<4096, 256, 0, stream>>>(input, Weff, bias,
                                             (float*)d_out);
  }
}